// Round 2
// baseline (115.907 us; speedup 1.0000x reference)
//
#include <hip/hip_runtime.h>

// S4D diagonal SSM kernel generation (ZOH, real_type='exp', rep=1)
// K[h,l] = sum_n Re( G[h,n] * w[h,n]^l ),  w = exp(dt*A),  G = 2*B*C*(w-1)/A.
//
// Round-2 structure:
//  - block = 512 threads (8 waves) per h; nb = t>>6 selects n-group [8nb,8nb+8),
//    tl = t&63 selects l-chunk [32tl, 32tl+32).  768 blocks x 8 waves
//    = 3 blocks/CU exactly -> ~75% occupancy (was 12.5%).
//  - order-2 REAL recurrence: r_{l+1} = c1*r_l - c2*r_{l-1}, c1=2Re(w),
//    c2=|w|^2 -> 3 lane-ops per (n,l) instead of 5 (complex form).
//  - adjacent n paired into float2 ext-vectors so the backend can emit
//    v_pk_mul_f32 / v_pk_fma_f32 (dual-issue fp32; falls back to scalar
//    harmlessly if not matched).
//  - init u = G*w^(32*tl) via 6-step branch-free bit-product from the LDS
//    table w^(32*2^k); all transcendentals once per (h,n) in setup wave.
//  - 3-stage LDS tree reduction over the 8 n-groups, [j][tl] layout
//    (lane-stride-1, bank-conflict-free).

typedef float v2f __attribute__((ext_vector_type(2)));

#define H_DIM 768
#define N_DIM 64
#define L_DIM 2048
#define TPB   512
#define LTH   64   // l-threads per h
#define LCH   32   // l per thread
#define NBITS 6    // bits of tl

__global__ __launch_bounds__(TPB, 6) void s4d_gen_kernel(
    const float* __restrict__ log_dt,
    const float* __restrict__ B_ri,
    const float* __restrict__ inv_A_real,
    const float* __restrict__ A_imag,
    const float* __restrict__ C_ri,
    float* __restrict__ out)
{
    __shared__ v2f  sW[N_DIM];          // w (r,i)
    __shared__ v2f  sG[N_DIM];          // G = 2*Cd (r,i)
    __shared__ v2f  sT[NBITS][N_DIM];   // w^(32*2^k)
    __shared__ v2f  sC1p[N_DIM / 2];    // c1 = 2Re(w), paired (n even, n+1)
    __shared__ v2f  sNC2p[N_DIM / 2];   // -|w|^2, paired
    __shared__ float sRed[4][LCH][LTH]; // reduction buffer, [grp][j][tl]

    const int h  = blockIdx.x;
    const int t  = threadIdx.x;
    const int nb = t >> 6;   // n-group 0..7
    const int tl = t & 63;   // l-chunk  0..63

    // ---- setup: one thread per n computes coefficients + power table ----
    if (t < N_DIM) {
        const int n   = t;
        const int idx = h * N_DIM + n;
        const float dt = expf(log_dt[h]);
        const float Ar = -expf(inv_A_real[idx]);
        const float Ai = A_imag[idx];
        const float e  = expf(Ar * dt);
        float s, c;
        sincosf(Ai * dt, &s, &c);
        const float wr = e * c, wi = e * s;
        const float inv = 1.0f / (Ar * Ar + Ai * Ai);
        const float nr = wr - 1.0f, ni = wi;
        const float qr = (nr * Ar + ni * Ai) * inv;
        const float qi = (ni * Ar - nr * Ai) * inv;
        const float Br = B_ri[2 * idx], Bi = B_ri[2 * idx + 1];
        const float Cr = C_ri[2 * idx], Ci = C_ri[2 * idx + 1];
        const float BCr = Br * Cr - Bi * Ci;
        const float BCi = Br * Ci + Bi * Cr;
        sG[n] = (v2f){2.0f * (BCr * qr - BCi * qi),
                      2.0f * (BCr * qi + BCi * qr)};
        sW[n] = (v2f){wr, wi};
        ((float*)sC1p)[n]  = 2.0f * wr;
        ((float*)sNC2p)[n] = -(wr * wr + wi * wi);
        // p = w^32 then table of repeated squares
        float pr = wr, pi = wi;
        #pragma unroll
        for (int k = 0; k < 5; ++k) { float t2 = pr*pr - pi*pi; pi = 2.0f*pr*pi; pr = t2; }
        #pragma unroll
        for (int k = 0; k < NBITS; ++k) {
            sT[k][n] = (v2f){pr, pi};
            float t2 = pr*pr - pi*pi; pi = 2.0f*pr*pi; pr = t2;
        }
    }
    __syncthreads();

    float acc[LCH];
    #pragma unroll
    for (int j = 0; j < LCH; ++j) acc[j] = 0.0f;

    const int nbase = nb * 8;

    // two outer iterations, each handling two n-pairs (4 n) -> 2 indep chains
    for (int pp = 0; pp < 2; ++pp) {
        const int na = nbase + 4 * pp;     // pair A: (na, na+1)
        const int nc = na + 2;             // pair B: (nc, nc+1)

        // ---- init: u = G * w^(32*tl) per n, branch-free bit product ----
        v2f uA0 = sG[na], uA1 = sG[na + 1];
        v2f uB0 = sG[nc], uB1 = sG[nc + 1];
        #pragma unroll
        for (int k = 0; k < NBITS; ++k) {
            const bool b = (tl >> k) & 1;
            const v2f tA0 = sT[k][na],     tA1 = sT[k][na + 1];
            const v2f tB0 = sT[k][nc],     tB1 = sT[k][nc + 1];
            const float mA0r = b ? tA0.x : 1.0f, mA0i = b ? tA0.y : 0.0f;
            const float mA1r = b ? tA1.x : 1.0f, mA1i = b ? tA1.y : 0.0f;
            const float mB0r = b ? tB0.x : 1.0f, mB0i = b ? tB0.y : 0.0f;
            const float mB1r = b ? tB1.x : 1.0f, mB1i = b ? tB1.y : 0.0f;
            float r0 = uA0.x*mA0r - uA0.y*mA0i; uA0.y = uA0.x*mA0i + uA0.y*mA0r; uA0.x = r0;
            float r1 = uA1.x*mA1r - uA1.y*mA1i; uA1.y = uA1.x*mA1i + uA1.y*mA1r; uA1.x = r1;
            float r2 = uB0.x*mB0r - uB0.y*mB0i; uB0.y = uB0.x*mB0i + uB0.y*mB0r; uB0.x = r2;
            float r3 = uB1.x*mB1r - uB1.y*mB1i; uB1.y = uB1.x*mB1i + uB1.y*mB1r; uB1.x = r3;
        }
        // r at l0 and l0+1 for each n, packed per pair
        const v2f wA0 = sW[na], wA1 = sW[na + 1];
        const v2f wB0 = sW[nc], wB1 = sW[nc + 1];
        v2f s0A = (v2f){uA0.x, uA1.x};
        v2f s1A = (v2f){wA0.x*uA0.x - wA0.y*uA0.y, wA1.x*uA1.x - wA1.y*uA1.y};
        v2f s0B = (v2f){uB0.x, uB1.x};
        v2f s1B = (v2f){wB0.x*uB0.x - wB0.y*uB0.y, wB1.x*uB1.x - wB1.y*uB1.y};
        const v2f c1A  = sC1p[na >> 1],  c1B  = sC1p[nc >> 1];
        const v2f nc2A = sNC2p[na >> 1], nc2B = sNC2p[nc >> 1];

        // ---- inner: order-2 real recurrence, packed over the pair ----
        #pragma unroll
        for (int j = 0; j < LCH; ++j) {
            acc[j] += (s0A.x + s0A.y) + (s0B.x + s0B.y);
            v2f tA = c1A * s1A;                               // v_pk_mul_f32
            v2f nA = __builtin_elementwise_fma(nc2A, s0A, tA); // v_pk_fma_f32
            s0A = s1A; s1A = nA;
            v2f tB = c1B * s1B;
            v2f nB = __builtin_elementwise_fma(nc2B, s0B, tB);
            s0B = s1B; s1B = nB;
        }
    }

    // ---- 3-stage tree reduction over the 8 n-groups ----
    if (nb >= 4) {
        #pragma unroll
        for (int j = 0; j < LCH; ++j) sRed[nb - 4][j][tl] = acc[j];
    }
    __syncthreads();
    if (nb < 4) {
        #pragma unroll
        for (int j = 0; j < LCH; ++j) acc[j] += sRed[nb][j][tl];
    }
    __syncthreads();
    if (nb == 2 || nb == 3) {
        #pragma unroll
        for (int j = 0; j < LCH; ++j) sRed[nb - 2][j][tl] = acc[j];
    }
    __syncthreads();
    if (nb < 2) {
        #pragma unroll
        for (int j = 0; j < LCH; ++j) acc[j] += sRed[nb][j][tl];
    }
    __syncthreads();
    if (nb == 1) {
        #pragma unroll
        for (int j = 0; j < LCH; ++j) sRed[0][j][tl] = acc[j];
    }
    __syncthreads();
    if (nb == 0) {
        #pragma unroll
        for (int j = 0; j < LCH; ++j) acc[j] += sRed[0][j][tl];
        float* op = out + (size_t)h * L_DIM + tl * LCH;
        #pragma unroll
        for (int j = 0; j < LCH; j += 4) {
            *reinterpret_cast<float4*>(op + j) =
                make_float4(acc[j], acc[j + 1], acc[j + 2], acc[j + 3]);
        }
    }
}

extern "C" void kernel_launch(void* const* d_in, const int* in_sizes, int n_in,
                              void* d_out, int out_size, void* d_ws, size_t ws_size,
                              hipStream_t stream) {
    const float* log_dt     = (const float*)d_in[0];
    const float* B_ri       = (const float*)d_in[1];
    const float* inv_A_real = (const float*)d_in[2];
    const float* A_imag     = (const float*)d_in[3];
    const float* C_ri       = (const float*)d_in[4];
    float* out = (float*)d_out;
    hipLaunchKernelGGL(s4d_gen_kernel, dim3(H_DIM), dim3(TPB), 0, stream,
                       log_dt, B_ri, inv_A_real, A_imag, C_ri, out);
}

// Round 3
// 76.563 us; speedup vs baseline: 1.5139x; 1.5139x over previous
//
#include <hip/hip_runtime.h>

// S4D diagonal SSM kernel generation (ZOH, real_type='exp', rep=1)
// K[h,l] = sum_n Re( G[h,n] * w[h,n]^l ),  w = exp(dt*A),  G = 2*B*C*(w-1)/A.
//
// Round-3:
//  - __launch_bounds__(512, 4): VGPR cap 128 (round 2's (512,6) forced
//    VGPR<=64 -> acc[] spilled to scratch -> 198 MB HBM traffic/dispatch).
//    Live set ~90 VGPRs -> no spill at cap 128.
//  - packed v2f accumulators: inner step is 2 pk_mul/pk_fma chains +
//    2 pk_adds = 6 wave-issues per (4n, l) (was 8). Horizontal add at exit.
//  - order-2 real recurrence r_{l+1} = 2Re(w) r_l - |w|^2 r_{l-1}.
//  - init u = G*w^(32*tl) via 6-step branch-free bit-product from LDS table.
//  - 3-stage LDS tree reduction over 8 n-groups, [j][tl] layout
//    (lane-stride-1, conflict-free b32).

typedef float v2f __attribute__((ext_vector_type(2)));

#define H_DIM 768
#define N_DIM 64
#define L_DIM 2048
#define TPB   512
#define LTH   64   // l-threads per h
#define LCH   32   // l per thread
#define NBITS 6    // bits of tl

__global__ __launch_bounds__(TPB, 4) void s4d_gen_kernel(
    const float* __restrict__ log_dt,
    const float* __restrict__ B_ri,
    const float* __restrict__ inv_A_real,
    const float* __restrict__ A_imag,
    const float* __restrict__ C_ri,
    float* __restrict__ out)
{
    __shared__ v2f  sW[N_DIM];          // w (r,i)
    __shared__ v2f  sG[N_DIM];          // G (r,i)
    __shared__ v2f  sT[NBITS][N_DIM];   // w^(32*2^k)
    __shared__ v2f  sC1p[N_DIM / 2];    // c1 = 2Re(w), paired (n, n+1)
    __shared__ v2f  sNC2p[N_DIM / 2];   // -|w|^2, paired
    __shared__ float sRed[4][LCH][LTH]; // reduction buffer, [grp][j][tl]

    const int h  = blockIdx.x;
    const int t  = threadIdx.x;
    const int nb = t >> 6;   // n-group 0..7
    const int tl = t & 63;   // l-chunk  0..63

    // ---- setup: one thread per n computes coefficients + power table ----
    if (t < N_DIM) {
        const int n   = t;
        const int idx = h * N_DIM + n;
        const float dt = expf(log_dt[h]);
        const float Ar = -expf(inv_A_real[idx]);
        const float Ai = A_imag[idx];
        const float e  = expf(Ar * dt);
        float s, c;
        sincosf(Ai * dt, &s, &c);
        const float wr = e * c, wi = e * s;
        const float inv = 1.0f / (Ar * Ar + Ai * Ai);
        const float nr = wr - 1.0f, ni = wi;
        const float qr = (nr * Ar + ni * Ai) * inv;
        const float qi = (ni * Ar - nr * Ai) * inv;
        const float Br = B_ri[2 * idx], Bi = B_ri[2 * idx + 1];
        const float Cr = C_ri[2 * idx], Ci = C_ri[2 * idx + 1];
        const float BCr = Br * Cr - Bi * Ci;
        const float BCi = Br * Ci + Bi * Cr;
        sG[n] = (v2f){2.0f * (BCr * qr - BCi * qi),
                      2.0f * (BCr * qi + BCi * qr)};
        sW[n] = (v2f){wr, wi};
        ((float*)sC1p)[n]  = 2.0f * wr;
        ((float*)sNC2p)[n] = -(wr * wr + wi * wi);
        float pr = wr, pi = wi;
        #pragma unroll
        for (int k = 0; k < 5; ++k) { float t2 = pr*pr - pi*pi; pi = 2.0f*pr*pi; pr = t2; }
        #pragma unroll
        for (int k = 0; k < NBITS; ++k) {
            sT[k][n] = (v2f){pr, pi};
            float t2 = pr*pr - pi*pi; pi = 2.0f*pr*pi; pr = t2;
        }
    }
    __syncthreads();

    v2f acc2[LCH];
    #pragma unroll
    for (int j = 0; j < LCH; ++j) acc2[j] = (v2f){0.0f, 0.0f};

    const int nbase = nb * 8;

    // two outer iterations, each handling two n-pairs (4 n) -> 2 indep chains
    for (int pp = 0; pp < 2; ++pp) {
        const int na = nbase + 4 * pp;     // pair A: (na, na+1)
        const int nc = na + 2;             // pair B: (nc, nc+1)

        // ---- init: u = G * w^(32*tl) per n, branch-free bit product ----
        v2f uA0 = sG[na], uA1 = sG[na + 1];
        v2f uB0 = sG[nc], uB1 = sG[nc + 1];
        #pragma unroll
        for (int k = 0; k < NBITS; ++k) {
            const bool b = (tl >> k) & 1;
            const v2f tA0 = sT[k][na],     tA1 = sT[k][na + 1];
            const v2f tB0 = sT[k][nc],     tB1 = sT[k][nc + 1];
            const float mA0r = b ? tA0.x : 1.0f, mA0i = b ? tA0.y : 0.0f;
            const float mA1r = b ? tA1.x : 1.0f, mA1i = b ? tA1.y : 0.0f;
            const float mB0r = b ? tB0.x : 1.0f, mB0i = b ? tB0.y : 0.0f;
            const float mB1r = b ? tB1.x : 1.0f, mB1i = b ? tB1.y : 0.0f;
            float r0 = uA0.x*mA0r - uA0.y*mA0i; uA0.y = uA0.x*mA0i + uA0.y*mA0r; uA0.x = r0;
            float r1 = uA1.x*mA1r - uA1.y*mA1i; uA1.y = uA1.x*mA1i + uA1.y*mA1r; uA1.x = r1;
            float r2 = uB0.x*mB0r - uB0.y*mB0i; uB0.y = uB0.x*mB0i + uB0.y*mB0r; uB0.x = r2;
            float r3 = uB1.x*mB1r - uB1.y*mB1i; uB1.y = uB1.x*mB1i + uB1.y*mB1r; uB1.x = r3;
        }
        // seed r at l0 and l0+1 for each n, packed per pair
        const v2f wA0 = sW[na], wA1 = sW[na + 1];
        const v2f wB0 = sW[nc], wB1 = sW[nc + 1];
        v2f s0A = (v2f){uA0.x, uA1.x};
        v2f s1A = (v2f){wA0.x*uA0.x - wA0.y*uA0.y, wA1.x*uA1.x - wA1.y*uA1.y};
        v2f s0B = (v2f){uB0.x, uB1.x};
        v2f s1B = (v2f){wB0.x*uB0.x - wB0.y*uB0.y, wB1.x*uB1.x - wB1.y*uB1.y};
        const v2f c1A  = sC1p[na >> 1],  c1B  = sC1p[nc >> 1];
        const v2f nc2A = sNC2p[na >> 1], nc2B = sNC2p[nc >> 1];

        // ---- inner: order-2 real recurrence, packed over the pair ----
        #pragma unroll
        for (int j = 0; j < LCH; ++j) {
            acc2[j] += s0A;                                    // v_pk_add_f32
            acc2[j] += s0B;                                    // v_pk_add_f32
            v2f tA = c1A * s1A;                                // v_pk_mul_f32
            v2f nA = __builtin_elementwise_fma(nc2A, s0A, tA); // v_pk_fma_f32
            s0A = s1A; s1A = nA;
            v2f tB = c1B * s1B;
            v2f nB = __builtin_elementwise_fma(nc2B, s0B, tB);
            s0B = s1B; s1B = nB;
        }
    }

    // horizontal add: pair -> scalar per j
    float acc[LCH];
    #pragma unroll
    for (int j = 0; j < LCH; ++j) acc[j] = acc2[j].x + acc2[j].y;

    // ---- 3-stage tree reduction over the 8 n-groups ----
    if (nb >= 4) {
        #pragma unroll
        for (int j = 0; j < LCH; ++j) sRed[nb - 4][j][tl] = acc[j];
    }
    __syncthreads();
    if (nb < 4) {
        #pragma unroll
        for (int j = 0; j < LCH; ++j) acc[j] += sRed[nb][j][tl];
    }
    __syncthreads();
    if (nb == 2 || nb == 3) {
        #pragma unroll
        for (int j = 0; j < LCH; ++j) sRed[nb - 2][j][tl] = acc[j];
    }
    __syncthreads();
    if (nb < 2) {
        #pragma unroll
        for (int j = 0; j < LCH; ++j) acc[j] += sRed[nb][j][tl];
    }
    __syncthreads();
    if (nb == 1) {
        #pragma unroll
        for (int j = 0; j < LCH; ++j) sRed[0][j][tl] = acc[j];
    }
    __syncthreads();
    if (nb == 0) {
        #pragma unroll
        for (int j = 0; j < LCH; ++j) acc[j] += sRed[0][j][tl];
        float* op = out + (size_t)h * L_DIM + tl * LCH;
        #pragma unroll
        for (int j = 0; j < LCH; j += 4) {
            *reinterpret_cast<float4*>(op + j) =
                make_float4(acc[j], acc[j + 1], acc[j + 2], acc[j + 3]);
        }
    }
}

extern "C" void kernel_launch(void* const* d_in, const int* in_sizes, int n_in,
                              void* d_out, int out_size, void* d_ws, size_t ws_size,
                              hipStream_t stream) {
    const float* log_dt     = (const float*)d_in[0];
    const float* B_ri       = (const float*)d_in[1];
    const float* inv_A_real = (const float*)d_in[2];
    const float* A_imag     = (const float*)d_in[3];
    const float* C_ri       = (const float*)d_in[4];
    float* out = (float*)d_out;
    hipLaunchKernelGGL(s4d_gen_kernel, dim3(H_DIM), dim3(TPB), 0, stream,
                       log_dt, B_ri, inv_A_real, A_imag, C_ri, out);
}

// Round 4
// 72.873 us; speedup vs baseline: 1.5905x; 1.0506x over previous
//
#include <hip/hip_runtime.h>
#include <math.h>

// S4D diagonal SSM kernel generation (ZOH, real_type='exp', rep=1)
// K[h,l] = sum_n Re( G[h,n] * w[h,n]^l ),  w = exp(dt*A),  G = 2*B*C*(w-1)/A.
//
// Round-4:
//  - block = 256 threads (4 waves): nb=t>>6 in 0..3 owns 16 n; tl=t&63 owns
//    l-chunk [32*tl, 32*tl+32). __launch_bounds__(256,3) -> VGPR cap 170,
//    LDS 18.5 KB -> EXACTLY 3 blocks/CU resident, grid 768 = 256 CU x 3,
//    zero scheduling tail (round 3: 8-wave blocks, 2/CU, 1.5 rounds).
//  - init via HW transcendentals instead of 6-step bit-product:
//    u = w^(32 tl) in polar form. Setup reduces phase(w^32) mod 1 rev in
//    double; per thread per n: v_fract + v_sin/v_cos (revolutions-native)
//    + v_exp for |w|^(32 tl), then 2 FMAs give the two real seeds
//    Re(G u), Re(G w u) directly. ~12 issues/n vs ~36 for bit-product.
//  - inner loop unchanged (validated r2/r3): order-2 real recurrence
//    r_{l+1} = 2Re(w) r_l - |w|^2 r_{l-1}, pair-packed v2f ->
//    v_pk_mul/v_pk_fma/v_pk_add, 6 issues per (4n, l).
//  - 2-stage LDS tree reduction over 4 n-groups, [j][tl] layout
//    (lane-stride-1 b32, conflict-free).

typedef float v2f __attribute__((ext_vector_type(2)));

#define H_DIM 768
#define N_DIM 64
#define L_DIM 2048
#define TPB   256
#define LTH   64   // l-threads per h
#define LCH   32   // l per thread

__global__ __launch_bounds__(TPB, 3) void s4d_gen_kernel(
    const float* __restrict__ log_dt,
    const float* __restrict__ B_ri,
    const float* __restrict__ inv_A_real,
    const float* __restrict__ A_imag,
    const float* __restrict__ C_ri,
    float* __restrict__ out)
{
    __shared__ float4 sP0[N_DIM];        // {r32f (revs of w^32 mod 1), l2m32 (log2|w^32|), Gr, Gi}
    __shared__ float4 sP1[N_DIM];        // {Gwr, Gwi, 0, 0}
    __shared__ v2f    sC1p[N_DIM / 2];   // c1 = 2Re(w), pair-packed
    __shared__ v2f    sNC2p[N_DIM / 2];  // -|w|^2, pair-packed
    __shared__ float  sRed[2][LCH][LTH]; // reduction buffer [grp][j][tl]

    const int h  = blockIdx.x;
    const int t  = threadIdx.x;
    const int nb = t >> 6;   // n-group 0..3 (wave-uniform)
    const int tl = t & 63;   // l-chunk  0..63

    // ---- setup: one thread per n ----
    if (t < N_DIM) {
        const int n   = t;
        const int idx = h * N_DIM + n;
        const float dt = expf(log_dt[h]);
        const float Ar = -expf(inv_A_real[idx]);
        const float Ai = A_imag[idx];
        const float dtAr = Ar * dt;
        const float dtAi = Ai * dt;
        const float e  = expf(dtAr);
        float s, c;
        sincosf(dtAi, &s, &c);
        const float wr = e * c, wi = e * s;
        const float inv = 1.0f / (Ar * Ar + Ai * Ai);
        const float nr = wr - 1.0f, ni = wi;
        const float qr = (nr * Ar + ni * Ai) * inv;
        const float qi = (ni * Ar - nr * Ai) * inv;
        const float Br = B_ri[2 * idx], Bi = B_ri[2 * idx + 1];
        const float Cr = C_ri[2 * idx], Ci = C_ri[2 * idx + 1];
        const float BCr = Br * Cr - Bi * Ci;
        const float BCi = Br * Ci + Bi * Cr;
        const float Gr = 2.0f * (BCr * qr - BCi * qi);
        const float Gi = 2.0f * (BCr * qi + BCi * qr);
        // phase of w^32 in revolutions, reduced mod 1 in double (setup-only)
        const double revs32 = (double)dtAi * (32.0 / (2.0 * M_PI));
        const float  r32f   = (float)(revs32 - floor(revs32));
        // log2 |w^32| = 32 * dtAr * log2(e)
        const float  l2m32  = dtAr * (32.0f * 1.4426950408889634f);
        sP0[n] = make_float4(r32f, l2m32, Gr, Gi);
        sP1[n] = make_float4(Gr * wr - Gi * wi, Gr * wi + Gi * wr, 0.0f, 0.0f);
        ((float*)sC1p)[n]  = 2.0f * wr;
        ((float*)sNC2p)[n] = -(wr * wr + wi * wi);
    }
    __syncthreads();

    v2f acc2[LCH];
    #pragma unroll
    for (int j = 0; j < LCH; ++j) acc2[j] = (v2f){0.0f, 0.0f};

    const int   nbase = nb * 16;
    const float tlf   = (float)tl;

    #pragma unroll 1
    for (int pp = 0; pp < 4; ++pp) {
        const int na = nbase + 4 * pp;   // pair A: (na, na+1)
        const int nc = na + 2;           // pair B: (nc, nc+1)

        const float4 pA0 = sP0[na], pA1 = sP0[na + 1];
        const float4 pB0 = sP0[nc], pB1 = sP0[nc + 1];
        const float4 qA0 = sP1[na], qA1 = sP1[na + 1];
        const float4 qB0 = sP1[nc], qB1 = sP1[nc + 1];

        // ---- polar init: u = w^(32 tl); seeds s0 = Re(G u), s1 = Re(G w u) ----
        const float fA0 = __builtin_amdgcn_fractf(pA0.x * tlf);
        const float fA1 = __builtin_amdgcn_fractf(pA1.x * tlf);
        const float fB0 = __builtin_amdgcn_fractf(pB0.x * tlf);
        const float fB1 = __builtin_amdgcn_fractf(pB1.x * tlf);
        const float snA0 = __builtin_amdgcn_sinf(fA0), csA0 = __builtin_amdgcn_cosf(fA0);
        const float snA1 = __builtin_amdgcn_sinf(fA1), csA1 = __builtin_amdgcn_cosf(fA1);
        const float snB0 = __builtin_amdgcn_sinf(fB0), csB0 = __builtin_amdgcn_cosf(fB0);
        const float snB1 = __builtin_amdgcn_sinf(fB1), csB1 = __builtin_amdgcn_cosf(fB1);
        const float mA0 = __builtin_amdgcn_exp2f(pA0.y * tlf);
        const float mA1 = __builtin_amdgcn_exp2f(pA1.y * tlf);
        const float mB0 = __builtin_amdgcn_exp2f(pB0.y * tlf);
        const float mB1 = __builtin_amdgcn_exp2f(pB1.y * tlf);
        const float urA0 = mA0 * csA0, uiA0 = mA0 * snA0;
        const float urA1 = mA1 * csA1, uiA1 = mA1 * snA1;
        const float urB0 = mB0 * csB0, uiB0 = mB0 * snB0;
        const float urB1 = mB1 * csB1, uiB1 = mB1 * snB1;

        v2f s0A = (v2f){fmaf(pA0.z, urA0, -(pA0.w * uiA0)),
                        fmaf(pA1.z, urA1, -(pA1.w * uiA1))};
        v2f s1A = (v2f){fmaf(qA0.x, urA0, -(qA0.y * uiA0)),
                        fmaf(qA1.x, urA1, -(qA1.y * uiA1))};
        v2f s0B = (v2f){fmaf(pB0.z, urB0, -(pB0.w * uiB0)),
                        fmaf(pB1.z, urB1, -(pB1.w * uiB1))};
        v2f s1B = (v2f){fmaf(qB0.x, urB0, -(qB0.y * uiB0)),
                        fmaf(qB1.x, urB1, -(qB1.y * uiB1))};

        const v2f c1A  = sC1p[na >> 1],  c1B  = sC1p[nc >> 1];
        const v2f nc2A = sNC2p[na >> 1], nc2B = sNC2p[nc >> 1];

        // ---- inner: order-2 real recurrence, pair-packed ----
        #pragma unroll
        for (int j = 0; j < LCH; ++j) {
            acc2[j] += s0A;                                    // v_pk_add_f32
            acc2[j] += s0B;                                    // v_pk_add_f32
            v2f tA = c1A * s1A;                                // v_pk_mul_f32
            v2f nA = __builtin_elementwise_fma(nc2A, s0A, tA); // v_pk_fma_f32
            s0A = s1A; s1A = nA;
            v2f tB = c1B * s1B;
            v2f nB = __builtin_elementwise_fma(nc2B, s0B, tB);
            s0B = s1B; s1B = nB;
        }
    }

    // horizontal add: pair -> scalar per j
    float acc[LCH];
    #pragma unroll
    for (int j = 0; j < LCH; ++j) acc[j] = acc2[j].x + acc2[j].y;

    // ---- 2-stage tree reduction over the 4 n-groups ----
    if (nb >= 2) {
        #pragma unroll
        for (int j = 0; j < LCH; ++j) sRed[nb - 2][j][tl] = acc[j];
    }
    __syncthreads();
    if (nb < 2) {
        #pragma unroll
        for (int j = 0; j < LCH; ++j) acc[j] += sRed[nb][j][tl];
    }
    __syncthreads();
    if (nb == 1) {
        #pragma unroll
        for (int j = 0; j < LCH; ++j) sRed[0][j][tl] = acc[j];
    }
    __syncthreads();
    if (nb == 0) {
        #pragma unroll
        for (int j = 0; j < LCH; ++j) acc[j] += sRed[0][j][tl];
        float* op = out + (size_t)h * L_DIM + tl * LCH;
        #pragma unroll
        for (int j = 0; j < LCH; j += 4) {
            *reinterpret_cast<float4*>(op + j) =
                make_float4(acc[j], acc[j + 1], acc[j + 2], acc[j + 3]);
        }
    }
}

extern "C" void kernel_launch(void* const* d_in, const int* in_sizes, int n_in,
                              void* d_out, int out_size, void* d_ws, size_t ws_size,
                              hipStream_t stream) {
    const float* log_dt     = (const float*)d_in[0];
    const float* B_ri       = (const float*)d_in[1];
    const float* inv_A_real = (const float*)d_in[2];
    const float* A_imag     = (const float*)d_in[3];
    const float* C_ri       = (const float*)d_in[4];
    float* out = (float*)d_out;
    hipLaunchKernelGGL(s4d_gen_kernel, dim3(H_DIM), dim3(TPB), 0, stream,
                       log_dt, B_ri, inv_A_real, A_imag, C_ri, out);
}